// Round 11
// baseline (272.652 us; speedup 1.0000x reference)
//
#include <hip/hip_runtime.h>
#include <hip/hip_bf16.h>

// VQ-EMA forward for z:(32,64,32,32) fp32, 1024 codes of dim 64.
// Outputs (flat, fp32): z_q (2097152) | loss (1) | counts (1024)
// MFMA distance via exact 3-way bf16 split; counts/sums via code-major
// LDS-accumulated scatter (NO global atomics). zf staged in d_out's z_q
// region (written by vq_dist, consumed by vq_scatter, then overwritten
// by vq_gather -- same-stream ordering guarantees safety).

#define N_ROWS   32768
#define N_CODES  1024
#define ZQ_ELEMS 2097152
#define CPB      4          // codes per scatter block

typedef __attribute__((ext_vector_type(8))) short short8;   // 8 bf16 (4 VGPR)
typedef __attribute__((ext_vector_type(4))) float f32x4;

__device__ __forceinline__ unsigned short f2bf(float x) {
    unsigned u = __float_as_uint(x);
    return (unsigned short)((u + 0x7fffu + ((u >> 16) & 1u)) >> 16);
}
__device__ __forceinline__ float bf2f(unsigned short h) {
    return __uint_as_float(((unsigned)h) << 16);
}

// ---------------- kernel 1: split emb -> 3 bf16 planes | enorm -------------
__global__ void vq_prep(const float* __restrict__ emb,
                        unsigned short* __restrict__ eH, unsigned short* __restrict__ eM,
                        unsigned short* __restrict__ eL, float* __restrict__ enorm) {
    const int g = blockIdx.x * 256 + threadIdx.x;
    if (g < 65536) {
        const float f = emb[g];
        const unsigned short h = f2bf(f);
        const float r1 = f - bf2f(h);
        const unsigned short m = f2bf(r1);
        const float r2 = r1 - bf2f(m);
        eH[g] = h; eM[g] = m; eL[g] = f2bf(r2);    // exact: f == H+M+L
    } else if (g < 65536 + N_CODES) {
        const int c = g - 65536;
        const float4* __restrict__ e4 = (const float4*)(emb + (c << 6));
        float s = 0.f;
        #pragma unroll
        for (int i = 0; i < 16; ++i) {             // sequential k (ref chain)
            const float4 v = e4[i];
            s = fmaf(v.x, v.x, s); s = fmaf(v.y, v.y, s);
            s = fmaf(v.z, v.z, s); s = fmaf(v.w, v.w, s);
        }
        enorm[c] = s;
    }
}

// ---------------- kernel 2: MFMA distance + argmin; writes idx + zf --------
// 256 blocks x 1024 thr (16 waves = 4 row-strips x 4 code-groups).
// Block: 128 rows x 1024 codes; 16 chunks of 64 codes staged via LDS.
#define MFMA_BF16 __builtin_amdgcn_mfma_f32_16x16x32_bf16

__global__ __launch_bounds__(1024) void vq_dist(
        const float* __restrict__ z,
        const unsigned short* __restrict__ eH, const unsigned short* __restrict__ eM,
        const unsigned short* __restrict__ eL, const float* __restrict__ enorm,
        int* __restrict__ idx_out, float* __restrict__ zf_out) {
    __shared__ unsigned short zH[128 * 72];   // [row][k] pad 72 (16B-aligned rows)
    __shared__ unsigned short zM[128 * 72];
    __shared__ unsigned short zL[128 * 72];
    __shared__ unsigned short esH[64 * 72];   // staged e chunk (64 codes)
    __shared__ unsigned short esM[64 * 72];
    __shared__ unsigned short esL[64 * 72];
    __shared__ float en_lds[N_CODES];
    __shared__ float bestS[4][128];
    __shared__ int   idxS[4][128];

    const int t    = threadIdx.x;
    const int bid  = blockIdx.x;
    const int r0   = bid * 128;
    const int b    = r0 >> 10;
    const int hw0  = r0 & 1023;

    // ---- stage z: read BCHW coalesced, split to 3 bf16 planes in LDS ----
    #pragma unroll
    for (int i = 0; i < 8; ++i) {
        const int cell = i * 1024 + t;
        const int row = cell & 127, c = cell >> 7;
        const float f = z[((b * 64 + c) << 10) + hw0 + row];
        const unsigned short h = f2bf(f);
        const float r1 = f - bf2f(h);
        const unsigned short m = f2bf(r1);
        const float r2 = r1 - bf2f(m);
        zH[row * 72 + c] = h;
        zM[row * 72 + c] = m;
        zL[row * 72 + c] = f2bf(r2);
    }
    en_lds[t] = enorm[t];
    __syncthreads();

    const int lane = t & 63, wid = t >> 6;
    const int wstrip = wid >> 2;              // 0..3 -> rows wstrip*32
    const int cg     = wid & 3;               // 0..3 -> codes cg*16 per chunk
    const int lr = lane & 15, lk = lane >> 4;

    // ---- hoist A-fragments: 2 row-tiles x {H,M,L} x {k0,k1} = 12 short8 ----
    short8 aH[2][2], aM[2][2], aL[2][2];
    #pragma unroll
    for (int tl = 0; tl < 2; ++tl) {
        const int ab = (wstrip * 32 + tl * 16 + lr) * 72 + lk * 8;
        aH[tl][0] = *(const short8*)&zH[ab]; aH[tl][1] = *(const short8*)&zH[ab + 32];
        aM[tl][0] = *(const short8*)&zM[ab]; aM[tl][1] = *(const short8*)&zM[ab + 32];
        aL[tl][0] = *(const short8*)&zL[ab]; aL[tl][1] = *(const short8*)&zL[ab + 32];
    }

    float best[2][4]; int bidx[2][4];
    #pragma unroll
    for (int tl = 0; tl < 2; ++tl)
        #pragma unroll
        for (int i = 0; i < 4; ++i) { best[tl][i] = INFINITY; bidx[tl][i] = 0; }

    // staging map: thread -> (cl, k4): cl = t>>4 (0..63), k4 = t&15
    const int cl = t >> 4, k4 = t & 15;
    const int ebyte = (cl << 6) + k4 * 4;     // element offset into 64-code chunk
    const int dsto  = cl * 72 + k4 * 4;       // LDS dest (short index), 8B aligned
    short4 st0, st1, st2;
    st0 = *(const short4*)&eH[ebyte];
    st1 = *(const short4*)&eM[ebyte];
    st2 = *(const short4*)&eL[ebyte];

    for (int ch = 0; ch < 16; ++ch) {
        __syncthreads();                       // prior chunk fully consumed
        *(short4*)&esH[dsto] = st0;
        *(short4*)&esM[dsto] = st1;
        *(short4*)&esL[dsto] = st2;
        __syncthreads();
        if (ch < 15) {                         // prefetch next chunk (drains under MFMA)
            const int off = (ch + 1) * 4096 + ebyte;
            st0 = *(const short4*)&eH[off];
            st1 = *(const short4*)&eM[off];
            st2 = *(const short4*)&eL[off];
        }

        // ---- B-fragments for this wave's 16 codes ----
        const int bb = (cg * 16 + lr) * 72 + lk * 8;
        const short8 bH0 = *(const short8*)&esH[bb];
        const short8 bH1 = *(const short8*)&esH[bb + 32];
        const short8 bM0 = *(const short8*)&esM[bb];
        const short8 bM1 = *(const short8*)&esM[bb + 32];
        const short8 bL0 = *(const short8*)&esL[bb];
        const short8 bL1 = *(const short8*)&esL[bb + 32];

        f32x4 a0 = {0.f, 0.f, 0.f, 0.f};
        f32x4 a1 = {0.f, 0.f, 0.f, 0.f};
        // product order per acc identical to R8/R10 (bit-identical scores)
        a0 = MFMA_BF16(aH[0][0], bH0, a0, 0, 0, 0);
        a1 = MFMA_BF16(aH[1][0], bH0, a1, 0, 0, 0);
        a0 = MFMA_BF16(aH[0][1], bH1, a0, 0, 0, 0);
        a1 = MFMA_BF16(aH[1][1], bH1, a1, 0, 0, 0);
        a0 = MFMA_BF16(aH[0][0], bM0, a0, 0, 0, 0);
        a1 = MFMA_BF16(aH[1][0], bM0, a1, 0, 0, 0);
        a0 = MFMA_BF16(aH[0][1], bM1, a0, 0, 0, 0);
        a1 = MFMA_BF16(aH[1][1], bM1, a1, 0, 0, 0);
        a0 = MFMA_BF16(aM[0][0], bH0, a0, 0, 0, 0);
        a1 = MFMA_BF16(aM[1][0], bH0, a1, 0, 0, 0);
        a0 = MFMA_BF16(aM[0][1], bH1, a0, 0, 0, 0);
        a1 = MFMA_BF16(aM[1][1], bH1, a1, 0, 0, 0);
        a0 = MFMA_BF16(aM[0][0], bM0, a0, 0, 0, 0);
        a1 = MFMA_BF16(aM[1][0], bM0, a1, 0, 0, 0);
        a0 = MFMA_BF16(aM[0][1], bM1, a0, 0, 0, 0);
        a1 = MFMA_BF16(aM[1][1], bM1, a1, 0, 0, 0);
        a0 = MFMA_BF16(aH[0][0], bL0, a0, 0, 0, 0);
        a1 = MFMA_BF16(aH[1][0], bL0, a1, 0, 0, 0);
        a0 = MFMA_BF16(aH[0][1], bL1, a0, 0, 0, 0);
        a1 = MFMA_BF16(aH[1][1], bL1, a1, 0, 0, 0);
        a0 = MFMA_BF16(aL[0][0], bH0, a0, 0, 0, 0);
        a1 = MFMA_BF16(aL[1][0], bH0, a1, 0, 0, 0);
        a0 = MFMA_BF16(aL[0][1], bH1, a0, 0, 0, 0);
        a1 = MFMA_BF16(aL[1][1], bH1, a1, 0, 0, 0);

        // ---- scores (en - 2*dot; row-constant ||z||^2 dropped) ----
        const int code = ch * 64 + cg * 16 + lr;     // strictly ascending in ch
        const float en_c = en_lds[code];
        #pragma unroll
        for (int i = 0; i < 4; ++i) {
            const float s0 = en_c - 2.0f * a0[i];
            if (s0 < best[0][i]) { best[0][i] = s0; bidx[0][i] = code; }
            const float s1 = en_c - 2.0f * a1[i];
            if (s1 < best[1][i]) { best[1][i] = s1; bidx[1][i] = code; }
        }
    }

    // ---- argmin across the 16 lr lanes (tie -> lower code index) ----
    #pragma unroll
    for (int off = 1; off < 16; off <<= 1) {
        #pragma unroll
        for (int tl = 0; tl < 2; ++tl)
            #pragma unroll
            for (int i = 0; i < 4; ++i) {
                const float os = __shfl_xor(best[tl][i], off);
                const int   oi = __shfl_xor(bidx[tl][i], off);
                if (os < best[tl][i] || (os == best[tl][i] && oi < bidx[tl][i])) {
                    best[tl][i] = os; bidx[tl][i] = oi;
                }
            }
    }
    if (lr == 0) {
        #pragma unroll
        for (int tl = 0; tl < 2; ++tl)
            #pragma unroll
            for (int i = 0; i < 4; ++i) {
                const int row = wstrip * 32 + tl * 16 + lk * 4 + i;  // C/D row map
                bestS[cg][row] = best[tl][i];
                idxS[cg][row]  = bidx[tl][i];
            }
    }
    __syncthreads();

    // ---- resolve code-groups (score, then lower-index tie-break) ----
    if (t < 128) {
        float bs = bestS[0][t]; int bi = idxS[0][t];
        #pragma unroll
        for (int g = 1; g < 4; ++g) {
            const float s = bestS[g][t]; const int ix = idxS[g][t];
            if (s < bs || (s == bs && ix < bi)) { bs = s; bi = ix; }
        }
        idx_out[r0 + t] = bi;
    }

    // ---- write zf row-major (exact reconstruct (H+M)+L == original fp32) --
    {
        const int k = t & 63, sub = t >> 6;
        #pragma unroll
        for (int i = 0; i < 8; ++i) {
            const int row = i * 16 + sub;
            const int o = row * 72 + k;
            zf_out[(r0 + row) * 64 + k] = (bf2f(zH[o]) + bf2f(zM[o])) + bf2f(zL[o]);
        }
    }
}

// ---------------- kernel 3: code-major counts/sums (LDS-accumulated) -------
// 256 blocks x 256 thr; block owns CPB=4 codes; no global atomics.
__global__ __launch_bounds__(256) void vq_scatter(
        const float* __restrict__ zf, const int* __restrict__ idx,
        float* __restrict__ counts, float* __restrict__ sums) {
    __shared__ float acc[CPB * 64];
    __shared__ float cnt[CPB];
    const int t  = threadIdx.x;
    const int c0 = blockIdx.x * CPB;
    for (int i = t; i < CPB * 64; i += 256) acc[i] = 0.f;
    if (t < CPB) cnt[t] = 0.f;
    __syncthreads();

    for (int r = t; r < N_ROWS; r += 256) {
        const int c = idx[r] - c0;
        if ((unsigned)c < (unsigned)CPB) {
            atomicAdd(&cnt[c], 1.0f);                       // LDS atomic
            const float4* __restrict__ zr = (const float4*)(zf + (r << 6));
            #pragma unroll
            for (int i = 0; i < 16; ++i) {
                const float4 v = zr[i];
                atomicAdd(&acc[(c << 6) + 4 * i + 0], v.x);
                atomicAdd(&acc[(c << 6) + 4 * i + 1], v.y);
                atomicAdd(&acc[(c << 6) + 4 * i + 2], v.z);
                atomicAdd(&acc[(c << 6) + 4 * i + 3], v.w);
            }
        }
    }
    __syncthreads();
    for (int i = t; i < CPB * 64; i += 256) sums[(c0 << 6) + i] = acc[i];
    if (t < CPB) counts[c0 + t] = cnt[t];
}

// ---------------- kernel 4: EMA update -> new_embed; counts out; loss=0 ----
__global__ void vq_ema(const float* __restrict__ counts, const float* __restrict__ sums,
                       const float* __restrict__ cs, const float* __restrict__ csum,
                       float* __restrict__ new_embed, float* __restrict__ out_counts,
                       float* __restrict__ out_loss) {
    const int g = blockIdx.x * 256 + threadIdx.x;   // 0 .. 65535
    const int c = g >> 6, d = g & 63;
    const float cnt = counts[c];
    const float nsize = 0.99f * cs[c] + 0.01f * cnt;
    const float nsum  = 0.99f * csum[g] + 0.01f * sums[g];
    new_embed[g] = nsum / (nsize + 1e-5f);
    if (d == 0) out_counts[c] = cnt;
    if (g == 0) out_loss[0] = 0.f;
}

// ---------------- kernel 5: gather z_q, straight-through, loss -------------
__global__ __launch_bounds__(256) void vq_gather(
        const float* __restrict__ z, const int* __restrict__ idx,
        const float* __restrict__ new_embed,
        float* __restrict__ out_zq, float* __restrict__ out_loss) {
    __shared__ float red[4];
    const int t  = threadIdx.x;
    const int r0 = blockIdx.x * 256;
    const int b  = r0 >> 10;
    const int hw = (r0 & 1023) + t;
    const int myidx = idx[r0 + t];

    const float4* __restrict__ er = (const float4*)(new_embed + (myidx << 6));
    float4 e4[16];
    #pragma unroll
    for (int i = 0; i < 16; ++i) e4[i] = er[i];

    float lsum = 0.f;
    #pragma unroll
    for (int c = 0; c < 64; ++c) {
        const float e  = ((const float*)e4)[c];
        const int  off = ((b * 64 + c) << 10) + hw;
        const float zv = z[off];
        const float diff = e - zv;                    // z_q - zp (fp32)
        out_zq[off] = zv + diff;                      // straight-through
        lsum = fmaf(diff, diff, lsum);
    }
    #pragma unroll
    for (int off = 32; off >= 1; off >>= 1) lsum += __shfl_down(lsum, off);
    if ((t & 63) == 0) red[t >> 6] = lsum;
    __syncthreads();
    if (t == 0) {
        const float s = red[0] + red[1] + red[2] + red[3];
        atomicAdd(out_loss, s * (0.25f / 2097152.0f));   // BETA/2^21 exact
    }
}

// ---------------------------------------------------------------------------
extern "C" void kernel_launch(void* const* d_in, const int* in_sizes, int n_in,
                              void* d_out, int out_size, void* d_ws, size_t ws_size,
                              hipStream_t stream) {
    const float* z    = (const float*)d_in[0];   // (32,64,32,32)
    const float* emb  = (const float*)d_in[1];   // (1024,64)
    const float* cs   = (const float*)d_in[2];   // (1024,)
    const float* csum = (const float*)d_in[3];   // (1024,64)
    float* out = (float*)d_out;

    // ws layout (floats / ints / shorts)
    float* counts     = (float*)d_ws;                    // 1024
    float* sums       = counts + N_CODES;                // 65536
    float* enorm_ws   = sums + 65536;                    // 1024
    float* new_embed  = enorm_ws + N_CODES;              // 65536
    int*   idx        = (int*)(new_embed + 65536);       // 32768 ints
    unsigned short* eH = (unsigned short*)(idx + 32768); // 65536 bf16 each
    unsigned short* eM = eH + 65536;
    unsigned short* eL = eM + 65536;

    // zf (row-major fp32 z) lives in d_out's z_q region: written by vq_dist,
    // read by vq_scatter, then overwritten by vq_gather (same stream).
    float* zf = out;

    vq_prep<<<260, 256, 0, stream>>>(emb, eH, eM, eL, enorm_ws);
    vq_dist<<<256, 1024, 0, stream>>>(z, eH, eM, eL, enorm_ws, idx, zf);
    vq_scatter<<<256, 256, 0, stream>>>(zf, idx, counts, sums);
    vq_ema<<<256, 256, 0, stream>>>(counts, sums, cs, csum, new_embed,
                                    out + ZQ_ELEMS + 1,   // counts out
                                    out + ZQ_ELEMS);      // loss out
    vq_gather<<<128, 256, 0, stream>>>(z, idx, new_embed, out, out + ZQ_ELEMS);
}